// Round 4
// baseline (255.981 us; speedup 1.0000x reference)
//
#include <hip/hip_runtime.h>
#include <cmath>

#define HH 512
#define WW 512
#define TW 32
#define THI 32          /* output rows per iteration */
#define NITER 16        /* HH / THI iterations per persistent block */
#define RING 64         /* LDS ring rows (power of 2); live window = 42 */
#define HPS 36          /* ring row stride in dwords (bank = (4r+c)%32, conflict-free) */
#define NTHREADS 256
#define C1F 0.0001f
#define C2F 0.0009f

struct GaussW { float w[11]; };

__device__ __forceinline__ void load16(const float* __restrict__ row, float v[16]) {
    *(float2*)&v[0]  = *(const float2*)(row);
    *(float4*)&v[2]  = *(const float4*)(row + 2);
    *(float4*)&v[6]  = *(const float4*)(row + 6);
    *(float4*)&v[10] = *(const float4*)(row + 10);
    *(float2*)&v[14] = *(const float2*)(row + 14);
}

// horizontal 11-tap conv of a,b,a^2,b^2 over 14 taps -> 4 output cols
__device__ __forceinline__ void conv_ab(const float a[14], const float b[14], const GaussW& gw,
                                        float sa[4], float sb[4], float saa[4], float sbb[4])
{
    #pragma unroll
    for (int o = 0; o < 4; o++) { sa[o] = 0.f; sb[o] = 0.f; saa[o] = 0.f; sbb[o] = 0.f; }
    #pragma unroll
    for (int k = 0; k < 11; k++) {
        float wk = gw.w[k];
        #pragma unroll
        for (int o = 0; o < 4; o++) {
            float av = a[o + k], bv = b[o + k];
            float wa = wk * av, wb = wk * bv;
            sa[o]  += wa;
            sb[o]  += wb;
            saa[o] += wa * av;
            sbb[o] += wb * bv;
        }
    }
}

// Persistent column-strip kernel: each block owns a 32-col x 512-row strip of
// one plane, iterating 16 tiles of 32 rows with a 64-row LDS ring.
// Pipeline per iteration: [issue global loads j+1] -> [phase C j] ->
// [butterfly+conv j+1 (vmcnt wait lands here, hidden under phase C)] ->
// barrier -> [ds_write j+1] -> barrier.
// Rationale: rounds 0-3 proved dur == FETCH/1.4TB/s regardless of compute
// (latency/MLP bound, convoy effect); round 1 proved 3.3TB/s achievable when
// vmem ops are spread in time. All 768 blocks co-resident (LDS 36.9KB -> >=4
// blocks/CU capacity, 3 needed) -> no convoy, loads always in flight.
__global__ __launch_bounds__(NTHREADS) void ssim_tile_kernel(
    const float* __restrict__ pred, const float* __restrict__ targ,
    float* __restrict__ partial, GaussW gw)
{
    __shared__ __align__(16) float hp[4][RING][HPS];
    __shared__ float wred[4];

    const int tid = threadIdx.x;
    const int bx = blockIdx.x;
    const int bz = blockIdx.y;
    const int gx0 = bx * TW;
    const size_t plane = (size_t)bz * (size_t)(HH * WW);
    const bool xinterior = (bx > 0) && (bx < (WW / TW) - 1);

    // ---- prologue: phase B for rows -5..36 (42 rows x 8 col-groups) ----
    for (int i = tid; i < 42 * 8; i += NTHREADS) {
        int r = i >> 3;
        int c0 = (i & 7) << 2;
        int gr = r - 5;
        int ri = gr & (RING - 1);
        float a[14], b[14];
        bool rowok = (unsigned)gr < (unsigned)HH;
        if (xinterior) {
            if (rowok) {
                float p[16], t[16];
                const float* pr = pred + plane + (size_t)gr * WW + (gx0 + c0 - 6);
                const float* tr = targ + plane + (size_t)gr * WW + (gx0 + c0 - 6);
                load16(pr, p);
                load16(tr, t);
                #pragma unroll
                for (int m = 0; m < 14; m++) { a[m] = p[m+1] + t[m+1]; b[m] = p[m+1] - t[m+1]; }
            } else {
                #pragma unroll
                for (int m = 0; m < 14; m++) { a[m] = 0.f; b[m] = 0.f; }
            }
        } else {
            if (rowok) {
                const size_t rb = plane + (size_t)gr * WW;
                int cbase = gx0 + c0 - 5;
                #pragma unroll
                for (int m = 0; m < 14; m++) {
                    int gc = cbase + m;
                    int cc = min(max(gc, 0), WW - 1);
                    float pv = pred[rb + cc];
                    float tv = targ[rb + cc];
                    float msk = ((unsigned)gc < (unsigned)WW) ? 1.f : 0.f;
                    a[m] = (pv + tv) * msk;
                    b[m] = (pv - tv) * msk;
                }
            } else {
                #pragma unroll
                for (int m = 0; m < 14; m++) { a[m] = 0.f; b[m] = 0.f; }
            }
        }
        float sa[4], sb[4], saa[4], sbb[4];
        conv_ab(a, b, gw, sa, sb, saa, sbb);
        *(float4*)&hp[0][ri][c0] = make_float4(sa[0],  sa[1],  sa[2],  sa[3]);
        *(float4*)&hp[1][ri][c0] = make_float4(sb[0],  sb[1],  sb[2],  sb[3]);
        *(float4*)&hp[2][ri][c0] = make_float4(saa[0], saa[1], saa[2], saa[3]);
        *(float4*)&hp[3][ri][c0] = make_float4(sbb[0], sbb[1], sbb[2], sbb[3]);
    }
    __syncthreads();

    // ---- steady loop: 16 iterations of {prefetch, phase C, conv, store} ----
    float local = 0.f;
    const int pc0 = (tid & 7) << 2;      // prefetch col-group base
    const int prr = tid >> 3;            // prefetch row within batch (0..31)
    const int cc0 = tid & 31;            // phase C col (0..31)
    const int cr0 = (tid >> 5) << 2;     // phase C row base (0..28)

    for (int j = 0; j < NITER; ++j) {
        const bool pf = (j < NITER - 1);

        // A) issue prefetch global loads for window j+1's 32 new rows
        float p[16], t[16];
        const int pgr = THI * (j + 1) + 5 + prr;   // rows 32j+37 .. 32j+68
        const bool prowok = pf && (pgr < HH);
        if (xinterior) {
            if (prowok) {
                const float* pr = pred + plane + (size_t)pgr * WW + (gx0 + pc0 - 6);
                const float* tr = targ + plane + (size_t)pgr * WW + (gx0 + pc0 - 6);
                load16(pr, p);
                load16(tr, t);
            }
        } else {
            if (prowok) {
                const size_t rb = plane + (size_t)pgr * WW;
                int cbase = gx0 + pc0 - 5;
                #pragma unroll
                for (int m = 0; m < 14; m++) {
                    int cc = min(max(cbase + m, 0), WW - 1);
                    p[m + 1] = pred[rb + cc];
                    t[m + 1] = targ[rb + cc];
                }
            }
        }

        // B) phase C on window j: vertical conv + SSIM, 4 rows x 1 col/thread
        {
            const int gr0 = THI * j + cr0 - 5;       // first of 14 read rows
            const int ri0 = gr0 & (RING - 1);
            float acc[4][4];
            #pragma unroll
            for (int f = 0; f < 4; f++)
                #pragma unroll
                for (int rr = 0; rr < 4; rr++)
                    acc[f][rr] = 0.f;

            if (ri0 <= RING - 14) {
                const float* hb = &hp[0][ri0][cc0];
                #pragma unroll
                for (int jj = 0; jj < 14; jj++) {
                    float v[4];
                    #pragma unroll
                    for (int f = 0; f < 4; f++)
                        v[f] = hb[f * (RING * HPS) + jj * HPS];
                    #pragma unroll
                    for (int rr = 0; rr < 4; rr++) {
                        int k = jj - rr;
                        if (k >= 0 && k < 11) {
                            float wk = gw.w[k];
                            #pragma unroll
                            for (int f = 0; f < 4; f++)
                                acc[f][rr] += wk * v[f];
                        }
                    }
                }
            } else {
                int ri = ri0;
                #pragma unroll
                for (int jj = 0; jj < 14; jj++) {
                    float v[4];
                    #pragma unroll
                    for (int f = 0; f < 4; f++)
                        v[f] = hp[f][ri][cc0];
                    ri = (ri + 1) & (RING - 1);
                    #pragma unroll
                    for (int rr = 0; rr < 4; rr++) {
                        int k = jj - rr;
                        if (k >= 0 && k < 11) {
                            float wk = gw.w[k];
                            #pragma unroll
                            for (int f = 0; f < 4; f++)
                                acc[f][rr] += wk * v[f];
                        }
                    }
                }
            }

            #pragma unroll
            for (int rr = 0; rr < 4; rr++) {
                float A  = acc[0][rr], Bv = acc[1][rr];
                float EA = acc[2][rr], EB = acc[3][rr];
                float A2 = A * A, B2 = Bv * Bv;
                float S  = 0.5f  * (A2 + B2);      // mu1^2 + mu2^2
                float P  = 0.25f * (A2 - B2);      // mu1 * mu2
                float Ep = 0.5f  * (EA + EB);      // e11 + e22
                float Ec = 0.25f * (EA - EB);      // e12
                float num = (2.f * P + C1F) * (2.f * (Ec - P) + C2F);
                float den = (S + C1F) * ((Ep - S) + C2F);
                local += num * __builtin_amdgcn_rcpf(den);
            }
        }

        // C) butterfly + horizontal conv of the prefetched rows (vmcnt wait
        //    lands here, hidden under phase C); store after the barrier.
        float sa[4], sb[4], saa[4], sbb[4];
        if (pf) {
            float a[14], b[14];
            if (prowok) {
                if (xinterior) {
                    #pragma unroll
                    for (int m = 0; m < 14; m++) { a[m] = p[m+1] + t[m+1]; b[m] = p[m+1] - t[m+1]; }
                } else {
                    int cbase = gx0 + pc0 - 5;
                    #pragma unroll
                    for (int m = 0; m < 14; m++) {
                        float msk = ((unsigned)(cbase + m) < (unsigned)WW) ? 1.f : 0.f;
                        a[m] = (p[m+1] + t[m+1]) * msk;
                        b[m] = (p[m+1] - t[m+1]) * msk;
                    }
                }
            } else {
                #pragma unroll
                for (int m = 0; m < 14; m++) { a[m] = 0.f; b[m] = 0.f; }
            }
            conv_ab(a, b, gw, sa, sb, saa, sbb);
        }
        __syncthreads();                 // all phase-C reads of window j done
        if (pf) {
            int ri = pgr & (RING - 1);
            *(float4*)&hp[0][ri][pc0] = make_float4(sa[0],  sa[1],  sa[2],  sa[3]);
            *(float4*)&hp[1][ri][pc0] = make_float4(sb[0],  sb[1],  sb[2],  sb[3]);
            *(float4*)&hp[2][ri][pc0] = make_float4(saa[0], saa[1], saa[2], saa[3]);
            *(float4*)&hp[3][ri][pc0] = make_float4(sbb[0], sbb[1], sbb[2], sbb[3]);
        }
        __syncthreads();                 // ring writes visible to next phase C
    }

    // ---- block reduction (4 waves) ----
    #pragma unroll
    for (int off = 32; off > 0; off >>= 1)
        local += __shfl_down(local, off, 64);
    int lane = tid & 63, wid = tid >> 6;
    if (lane == 0) wred[wid] = local;
    __syncthreads();
    if (tid == 0) {
        int bid = blockIdx.y * gridDim.x + blockIdx.x;
        partial[bid] = wred[0] + wred[1] + wred[2] + wred[3];
    }
}

__global__ __launch_bounds__(256) void ssim_finalize_kernel(
    const float* __restrict__ partial, int n, float inv_count,
    float* __restrict__ out)
{
    __shared__ float sm[4];
    float s = 0.f;
    for (int i = threadIdx.x; i < n; i += 256)
        s += partial[i];
    #pragma unroll
    for (int off = 32; off > 0; off >>= 1)
        s += __shfl_down(s, off, 64);
    int lane = threadIdx.x & 63, wid = threadIdx.x >> 6;
    if (lane == 0) sm[wid] = s;
    __syncthreads();
    if (threadIdx.x == 0)
        out[0] = 1.0f - (sm[0] + sm[1] + sm[2] + sm[3]) * inv_count;
}

extern "C" void kernel_launch(void* const* d_in, const int* in_sizes, int n_in,
                              void* d_out, int out_size, void* d_ws, size_t ws_size,
                              hipStream_t stream)
{
    const float* pred = (const float*)d_in[0];
    const float* targ = (const float*)d_in[1];
    float* out = (float*)d_out;
    float* partial = (float*)d_ws;

    const int total = in_sizes[0];                 // 16*3*512*512 = 12582912
    const int nplanes = total / (HH * WW);         // 48

    GaussW gw;
    double g[11], s = 0.0;
    for (int i = 0; i < 11; i++) {
        double d = (double)(i - 5);
        g[i] = exp(-d * d / 4.5);
        s += g[i];
    }
    for (int i = 0; i < 11; i++) gw.w[i] = (float)(g[i] / s);

    dim3 grid(WW / TW, nplanes);                   // 16 x 48 = 768 persistent blocks
    ssim_tile_kernel<<<grid, NTHREADS, 0, stream>>>(pred, targ, partial, gw);

    const int nblocks = (WW / TW) * nplanes;       // 768
    const float inv_count = 1.0f / (float)total;
    ssim_finalize_kernel<<<1, 256, 0, stream>>>(partial, nblocks, inv_count, out);
}

// Round 5
// 235.693 us; speedup vs baseline: 1.0861x; 1.0861x over previous
//
#include <hip/hip_runtime.h>
#include <cmath>

#define HH 512
#define WW 512
#define TW 32
#define TH 32          /* output rows per tile */
#define INH 42         /* TH + 10 halo rows */
#define HPS 36         /* hp row stride in dwords (bank = (4r+c)%32, conflict-free) */
#define NTHREADS 256   /* 4 waves; LDS 24.2KB -> 6 blocks/CU = 24 waves/CU static */
#define NXT 16         /* x tiles */
#define NYT 16         /* y tiles */
#define C1F 0.0001f
#define C2F 0.0009f

struct GaussW { float w[11]; };

// R5: revert to proven R3 structure; two changes only.
// (1) 32x32 tile @256thr: LDS 24.2KB -> 6 blocks/CU co-resident (was 3).
//     Theory: achieved HBM BW (pinned ~1.4 TB/s) tracks concurrent
//     per-CU load bursts; R1 proved 3.3 TB/s sustainable, R4 proved
//     fewer/smaller bursts -> 0.84. Double the resident blocks.
// (2) XCD-bijective remap (12288 blocks % 8 == 0): each XCD owns 6
//     whole planes with bx/by-neighbor tiles temporally adjacent ->
//     halo lines dedup in L2. R4 proved the 1.4x overfetch is
//     horizontal/line-granular (vertical ring gave FETCH == 141MB),
//     i.e. an L2 cross-XCD locality loss.
// VGPR bound (256,6) caps at 85; natural ~56-64 (R3) -> no spill.
__global__ __launch_bounds__(NTHREADS, 6) void ssim_tile_kernel(
    const float* __restrict__ pred, const float* __restrict__ targ,
    float* __restrict__ partial, GaussW gw)
{
    __shared__ __align__(16) float hp[4][INH][HPS];
    __shared__ float wred[4];

    const int tid = threadIdx.x;

    // ---- XCD-bijective work remap: lid%8 = hw XCD (round-robin) ----
    const int lid = (blockIdx.z * gridDim.y + blockIdx.y) * gridDim.x + blockIdx.x;
    const int wi  = (lid & 7) * ((NXT * NYT * 48) / 8) + (lid >> 3);
    const int bx  = wi & (NXT - 1);
    const int by  = (wi >> 4) & (NYT - 1);
    const int bz  = wi >> 8;

    const int gx0 = bx * TW;
    const int gy0 = by * TH - 5;
    const size_t plane = (size_t)bz * (size_t)(HH * WW);

    const bool xinterior = (bx > 0) && (bx < NXT - 1);

    // ---- Phase B: horizontal Gaussian on (a,b,a^2,b^2) from global ----
    // 336 tasks: 42 rows x 8 col-groups, each computes 4 output cols.
    if (xinterior) {
        for (int i = tid; i < INH * 8; i += NTHREADS) {
            int r = i >> 3;
            int c0 = (i & 7) << 2;
            int gr = gy0 + r;
            // p[m]/t[m] hold input col c0-6+m, m=0..15 (need m=1..14)
            float p[16], t[16];
            if ((unsigned)gr < (unsigned)HH) {
                const float* prow = pred + plane + (size_t)gr * WW + (gx0 + c0 - 6);
                const float* trow = targ + plane + (size_t)gr * WW + (gx0 + c0 - 6);
                *(float2*)&p[0]  = *(const float2*)(prow);
                *(float4*)&p[2]  = *(const float4*)(prow + 2);
                *(float4*)&p[6]  = *(const float4*)(prow + 6);
                *(float4*)&p[10] = *(const float4*)(prow + 10);
                *(float2*)&p[14] = *(const float2*)(prow + 14);
                *(float2*)&t[0]  = *(const float2*)(trow);
                *(float4*)&t[2]  = *(const float4*)(trow + 2);
                *(float4*)&t[6]  = *(const float4*)(trow + 6);
                *(float4*)&t[10] = *(const float4*)(trow + 10);
                *(float2*)&t[14] = *(const float2*)(trow + 14);
            } else {
                #pragma unroll
                for (int m = 0; m < 16; m++) { p[m] = 0.f; t[m] = 0.f; }
            }

            // in-place butterfly: p[m] <- a = p+t, t[m] <- b = p-t
            #pragma unroll
            for (int m = 1; m < 15; m++) {
                float pv = p[m], tv = t[m];
                p[m] = pv + tv;
                t[m] = pv - tv;
            }

            float sa[4]  = {0,0,0,0}, sb[4]  = {0,0,0,0};
            float saa[4] = {0,0,0,0}, sbb[4] = {0,0,0,0};
            #pragma unroll
            for (int k = 0; k < 11; k++) {
                float wk = gw.w[k];
                #pragma unroll
                for (int o = 0; o < 4; o++) {
                    float av = p[o + k + 1], bv = t[o + k + 1];
                    float wa = wk * av, wb = wk * bv;
                    sa[o]  += wa;
                    sb[o]  += wb;
                    saa[o] += wa * av;
                    sbb[o] += wb * bv;
                }
            }
            *(float4*)&hp[0][r][c0] = make_float4(sa[0],  sa[1],  sa[2],  sa[3]);
            *(float4*)&hp[1][r][c0] = make_float4(sb[0],  sb[1],  sb[2],  sb[3]);
            *(float4*)&hp[2][r][c0] = make_float4(saa[0], saa[1], saa[2], saa[3]);
            *(float4*)&hp[3][r][c0] = make_float4(sbb[0], sbb[1], sbb[2], sbb[3]);
        }
    } else {
        for (int i = tid; i < INH * 8; i += NTHREADS) {
            int r = i >> 3;
            int c0 = (i & 7) << 2;
            int gr = gy0 + r;
            float p[14], t[14];
            if ((unsigned)gr < (unsigned)HH) {
                const size_t rb = plane + (size_t)gr * WW;
                int cbase = gx0 + c0 - 5;
                #pragma unroll
                for (int m = 0; m < 14; m++) {
                    int gc = cbase + m;
                    int cc = min(max(gc, 0), WW - 1);
                    bool in = (unsigned)gc < (unsigned)WW;
                    float pv = pred[rb + cc];
                    float tv = targ[rb + cc];
                    p[m] = in ? pv : 0.f;
                    t[m] = in ? tv : 0.f;
                }
            } else {
                #pragma unroll
                for (int m = 0; m < 14; m++) { p[m] = 0.f; t[m] = 0.f; }
            }

            #pragma unroll
            for (int m = 0; m < 14; m++) {
                float pv = p[m], tv = t[m];
                p[m] = pv + tv;
                t[m] = pv - tv;
            }

            float sa[4]  = {0,0,0,0}, sb[4]  = {0,0,0,0};
            float saa[4] = {0,0,0,0}, sbb[4] = {0,0,0,0};
            #pragma unroll
            for (int k = 0; k < 11; k++) {
                float wk = gw.w[k];
                #pragma unroll
                for (int o = 0; o < 4; o++) {
                    float av = p[o + k], bv = t[o + k];
                    float wa = wk * av, wb = wk * bv;
                    sa[o]  += wa;
                    sb[o]  += wb;
                    saa[o] += wa * av;
                    sbb[o] += wb * bv;
                }
            }
            *(float4*)&hp[0][r][c0] = make_float4(sa[0],  sa[1],  sa[2],  sa[3]);
            *(float4*)&hp[1][r][c0] = make_float4(sb[0],  sb[1],  sb[2],  sb[3]);
            *(float4*)&hp[2][r][c0] = make_float4(saa[0], saa[1], saa[2], saa[3]);
            *(float4*)&hp[3][r][c0] = make_float4(sbb[0], sbb[1], sbb[2], sbb[3]);
        }
    }
    __syncthreads();

    // ---- Phase C: vertical Gaussian, 4 rows x 1 col per thread + SSIM ----
    // 256 threads x 4 outputs = 1024 = 32x32 tile. Conflict-free b32 reads.
    float local = 0.f;
    {
        const int c0 = tid & 31;            // 0..31
        const int r0 = (tid >> 5) << 2;     // 0..28
        const float* hbase = &hp[0][r0][c0];

        float acc[4][4];
        #pragma unroll
        for (int f = 0; f < 4; f++)
            #pragma unroll
            for (int rr = 0; rr < 4; rr++)
                acc[f][rr] = 0.f;

        #pragma unroll
        for (int jj = 0; jj < 14; jj++) {
            float v[4];
            #pragma unroll
            for (int f = 0; f < 4; f++)
                v[f] = hbase[f * (INH * HPS) + jj * HPS];
            #pragma unroll
            for (int rr = 0; rr < 4; rr++) {
                int k = jj - rr;
                if (k >= 0 && k < 11) {
                    float wk = gw.w[k];
                    #pragma unroll
                    for (int f = 0; f < 4; f++)
                        acc[f][rr] += wk * v[f];
                }
            }
        }

        #pragma unroll
        for (int rr = 0; rr < 4; rr++) {
            float A  = acc[0][rr], Bv = acc[1][rr];
            float EA = acc[2][rr], EB = acc[3][rr];
            float A2 = A * A, B2 = Bv * Bv;
            float S  = 0.5f  * (A2 + B2);      // mu1^2 + mu2^2
            float P  = 0.25f * (A2 - B2);      // mu1 * mu2
            float Ep = 0.5f  * (EA + EB);      // e11 + e22
            float Ec = 0.25f * (EA - EB);      // e12
            float num = (2.f * P + C1F) * (2.f * (Ec - P) + C2F);
            float den = (S + C1F) * ((Ep - S) + C2F);
            local += num * __builtin_amdgcn_rcpf(den);
        }
    }

    // ---- block reduction (4 waves) ----
    #pragma unroll
    for (int off = 32; off > 0; off >>= 1)
        local += __shfl_down(local, off, 64);
    int lane = tid & 63, wid = tid >> 6;
    if (lane == 0) wred[wid] = local;
    __syncthreads();
    if (tid == 0)
        partial[lid] = wred[0] + wred[1] + wred[2] + wred[3];
}

__global__ __launch_bounds__(256) void ssim_finalize_kernel(
    const float* __restrict__ partial, int n, float inv_count,
    float* __restrict__ out)
{
    __shared__ float sm[4];
    float s = 0.f;
    for (int i = threadIdx.x; i < n; i += 256)
        s += partial[i];
    #pragma unroll
    for (int off = 32; off > 0; off >>= 1)
        s += __shfl_down(s, off, 64);
    int lane = threadIdx.x & 63, wid = threadIdx.x >> 6;
    if (lane == 0) sm[wid] = s;
    __syncthreads();
    if (threadIdx.x == 0)
        out[0] = 1.0f - (sm[0] + sm[1] + sm[2] + sm[3]) * inv_count;
}

extern "C" void kernel_launch(void* const* d_in, const int* in_sizes, int n_in,
                              void* d_out, int out_size, void* d_ws, size_t ws_size,
                              hipStream_t stream)
{
    const float* pred = (const float*)d_in[0];
    const float* targ = (const float*)d_in[1];
    float* out = (float*)d_out;
    float* partial = (float*)d_ws;

    const int total = in_sizes[0];                 // 16*3*512*512 = 12582912
    const int nplanes = total / (HH * WW);         // 48

    GaussW gw;
    double g[11], s = 0.0;
    for (int i = 0; i < 11; i++) {
        double d = (double)(i - 5);
        g[i] = exp(-d * d / 4.5);
        s += g[i];
    }
    for (int i = 0; i < 11; i++) gw.w[i] = (float)(g[i] / s);

    dim3 grid(NXT, NYT, nplanes);                  // 16 x 16 x 48 = 12288 blocks
    ssim_tile_kernel<<<grid, NTHREADS, 0, stream>>>(pred, targ, partial, gw);

    const int nblocks = NXT * NYT * nplanes;       // 12288
    const float inv_count = 1.0f / (float)total;
    ssim_finalize_kernel<<<1, 256, 0, stream>>>(partial, nblocks, inv_count, out);
}

// Round 6
// 180.977 us; speedup vs baseline: 1.4144x; 1.3023x over previous
//
#include <hip/hip_runtime.h>
#include <cmath>

#define HH 512
#define WW 512
#define TW 32
#define TH 32          /* output rows per tile */
#define INH 42         /* TH + 10 halo rows */
#define HPS 36         /* hp row stride in dwords (bank = (4r+c)%32, conflict-free) */
#define NTHREADS 256   /* 4 waves; LDS 24.6KB -> 6 blocks/CU = 24 waves/CU static */
#define NXT 16         /* x tiles */
#define NYT 16         /* y tiles */
#define C1F 0.0001f
#define C2F 0.0009f

struct GaussW { float w[11]; };

// R6 = R5 minus the launch_bounds min-waves arg.
// CONFIRMED twice (R1, R5): any min-waves hint on this kernel forces
// VGPR=40 + scratch spill (WRITE_SIZE 0.2 -> 162-363 MB). LDS alone
// (24.6 KB -> 6 blocks/CU) provides the residency we want; natural
// VGPR ~56-64 allows far more waves than LDS does, so no bound needed.
// R5's clean-pass counters validated both structural changes:
//   FETCH 141 -> 68 MB (XCD remap dedups halo + L3 retention),
//   Occupancy ~50% (6 blocks/CU resident).
__global__ __launch_bounds__(NTHREADS) void ssim_tile_kernel(
    const float* __restrict__ pred, const float* __restrict__ targ,
    float* __restrict__ partial, GaussW gw)
{
    __shared__ __align__(16) float hp[4][INH][HPS];
    __shared__ float wred[4];

    const int tid = threadIdx.x;

    // ---- XCD-bijective work remap: lid%8 = hw XCD (round-robin) ----
    const int lid = (blockIdx.z * gridDim.y + blockIdx.y) * gridDim.x + blockIdx.x;
    const int wi  = (lid & 7) * ((NXT * NYT * 48) / 8) + (lid >> 3);
    const int bx  = wi & (NXT - 1);
    const int by  = (wi >> 4) & (NYT - 1);
    const int bz  = wi >> 8;

    const int gx0 = bx * TW;
    const int gy0 = by * TH - 5;
    const size_t plane = (size_t)bz * (size_t)(HH * WW);

    const bool xinterior = (bx > 0) && (bx < NXT - 1);

    // ---- Phase B: horizontal Gaussian on (a,b,a^2,b^2) from global ----
    // 336 tasks: 42 rows x 8 col-groups, each computes 4 output cols.
    if (xinterior) {
        for (int i = tid; i < INH * 8; i += NTHREADS) {
            int r = i >> 3;
            int c0 = (i & 7) << 2;
            int gr = gy0 + r;
            // p[m]/t[m] hold input col c0-6+m, m=0..15 (need m=1..14)
            float p[16], t[16];
            if ((unsigned)gr < (unsigned)HH) {
                const float* prow = pred + plane + (size_t)gr * WW + (gx0 + c0 - 6);
                const float* trow = targ + plane + (size_t)gr * WW + (gx0 + c0 - 6);
                *(float2*)&p[0]  = *(const float2*)(prow);
                *(float4*)&p[2]  = *(const float4*)(prow + 2);
                *(float4*)&p[6]  = *(const float4*)(prow + 6);
                *(float4*)&p[10] = *(const float4*)(prow + 10);
                *(float2*)&p[14] = *(const float2*)(prow + 14);
                *(float2*)&t[0]  = *(const float2*)(trow);
                *(float4*)&t[2]  = *(const float4*)(trow + 2);
                *(float4*)&t[6]  = *(const float4*)(trow + 6);
                *(float4*)&t[10] = *(const float4*)(trow + 10);
                *(float2*)&t[14] = *(const float2*)(trow + 14);
            } else {
                #pragma unroll
                for (int m = 0; m < 16; m++) { p[m] = 0.f; t[m] = 0.f; }
            }

            // in-place butterfly: p[m] <- a = p+t, t[m] <- b = p-t
            #pragma unroll
            for (int m = 1; m < 15; m++) {
                float pv = p[m], tv = t[m];
                p[m] = pv + tv;
                t[m] = pv - tv;
            }

            float sa[4]  = {0,0,0,0}, sb[4]  = {0,0,0,0};
            float saa[4] = {0,0,0,0}, sbb[4] = {0,0,0,0};
            #pragma unroll
            for (int k = 0; k < 11; k++) {
                float wk = gw.w[k];
                #pragma unroll
                for (int o = 0; o < 4; o++) {
                    float av = p[o + k + 1], bv = t[o + k + 1];
                    float wa = wk * av, wb = wk * bv;
                    sa[o]  += wa;
                    sb[o]  += wb;
                    saa[o] += wa * av;
                    sbb[o] += wb * bv;
                }
            }
            *(float4*)&hp[0][r][c0] = make_float4(sa[0],  sa[1],  sa[2],  sa[3]);
            *(float4*)&hp[1][r][c0] = make_float4(sb[0],  sb[1],  sb[2],  sb[3]);
            *(float4*)&hp[2][r][c0] = make_float4(saa[0], saa[1], saa[2], saa[3]);
            *(float4*)&hp[3][r][c0] = make_float4(sbb[0], sbb[1], sbb[2], sbb[3]);
        }
    } else {
        for (int i = tid; i < INH * 8; i += NTHREADS) {
            int r = i >> 3;
            int c0 = (i & 7) << 2;
            int gr = gy0 + r;
            float p[14], t[14];
            if ((unsigned)gr < (unsigned)HH) {
                const size_t rb = plane + (size_t)gr * WW;
                int cbase = gx0 + c0 - 5;
                #pragma unroll
                for (int m = 0; m < 14; m++) {
                    int gc = cbase + m;
                    int cc = min(max(gc, 0), WW - 1);
                    bool in = (unsigned)gc < (unsigned)WW;
                    float pv = pred[rb + cc];
                    float tv = targ[rb + cc];
                    p[m] = in ? pv : 0.f;
                    t[m] = in ? tv : 0.f;
                }
            } else {
                #pragma unroll
                for (int m = 0; m < 14; m++) { p[m] = 0.f; t[m] = 0.f; }
            }

            #pragma unroll
            for (int m = 0; m < 14; m++) {
                float pv = p[m], tv = t[m];
                p[m] = pv + tv;
                t[m] = pv - tv;
            }

            float sa[4]  = {0,0,0,0}, sb[4]  = {0,0,0,0};
            float saa[4] = {0,0,0,0}, sbb[4] = {0,0,0,0};
            #pragma unroll
            for (int k = 0; k < 11; k++) {
                float wk = gw.w[k];
                #pragma unroll
                for (int o = 0; o < 4; o++) {
                    float av = p[o + k], bv = t[o + k];
                    float wa = wk * av, wb = wk * bv;
                    sa[o]  += wa;
                    sb[o]  += wb;
                    saa[o] += wa * av;
                    sbb[o] += wb * bv;
                }
            }
            *(float4*)&hp[0][r][c0] = make_float4(sa[0],  sa[1],  sa[2],  sa[3]);
            *(float4*)&hp[1][r][c0] = make_float4(sb[0],  sb[1],  sb[2],  sb[3]);
            *(float4*)&hp[2][r][c0] = make_float4(saa[0], saa[1], saa[2], saa[3]);
            *(float4*)&hp[3][r][c0] = make_float4(sbb[0], sbb[1], sbb[2], sbb[3]);
        }
    }
    __syncthreads();

    // ---- Phase C: vertical Gaussian, 4 rows x 1 col per thread + SSIM ----
    // 256 threads x 4 outputs = 1024 = 32x32 tile. Conflict-free b32 reads.
    float local = 0.f;
    {
        const int c0 = tid & 31;            // 0..31
        const int r0 = (tid >> 5) << 2;     // 0..28
        const float* hbase = &hp[0][r0][c0];

        float acc[4][4];
        #pragma unroll
        for (int f = 0; f < 4; f++)
            #pragma unroll
            for (int rr = 0; rr < 4; rr++)
                acc[f][rr] = 0.f;

        #pragma unroll
        for (int jj = 0; jj < 14; jj++) {
            float v[4];
            #pragma unroll
            for (int f = 0; f < 4; f++)
                v[f] = hbase[f * (INH * HPS) + jj * HPS];
            #pragma unroll
            for (int rr = 0; rr < 4; rr++) {
                int k = jj - rr;
                if (k >= 0 && k < 11) {
                    float wk = gw.w[k];
                    #pragma unroll
                    for (int f = 0; f < 4; f++)
                        acc[f][rr] += wk * v[f];
                }
            }
        }

        #pragma unroll
        for (int rr = 0; rr < 4; rr++) {
            float A  = acc[0][rr], Bv = acc[1][rr];
            float EA = acc[2][rr], EB = acc[3][rr];
            float A2 = A * A, B2 = Bv * Bv;
            float S  = 0.5f  * (A2 + B2);      // mu1^2 + mu2^2
            float P  = 0.25f * (A2 - B2);      // mu1 * mu2
            float Ep = 0.5f  * (EA + EB);      // e11 + e22
            float Ec = 0.25f * (EA - EB);      // e12
            float num = (2.f * P + C1F) * (2.f * (Ec - P) + C2F);
            float den = (S + C1F) * ((Ep - S) + C2F);
            local += num * __builtin_amdgcn_rcpf(den);
        }
    }

    // ---- block reduction (4 waves) ----
    #pragma unroll
    for (int off = 32; off > 0; off >>= 1)
        local += __shfl_down(local, off, 64);
    int lane = tid & 63, wid = tid >> 6;
    if (lane == 0) wred[wid] = local;
    __syncthreads();
    if (tid == 0)
        partial[lid] = wred[0] + wred[1] + wred[2] + wred[3];
}

__global__ __launch_bounds__(256) void ssim_finalize_kernel(
    const float* __restrict__ partial, int n, float inv_count,
    float* __restrict__ out)
{
    __shared__ float sm[4];
    float s = 0.f;
    for (int i = threadIdx.x; i < n; i += 256)
        s += partial[i];
    #pragma unroll
    for (int off = 32; off > 0; off >>= 1)
        s += __shfl_down(s, off, 64);
    int lane = threadIdx.x & 63, wid = threadIdx.x >> 6;
    if (lane == 0) sm[wid] = s;
    __syncthreads();
    if (threadIdx.x == 0)
        out[0] = 1.0f - (sm[0] + sm[1] + sm[2] + sm[3]) * inv_count;
}

extern "C" void kernel_launch(void* const* d_in, const int* in_sizes, int n_in,
                              void* d_out, int out_size, void* d_ws, size_t ws_size,
                              hipStream_t stream)
{
    const float* pred = (const float*)d_in[0];
    const float* targ = (const float*)d_in[1];
    float* out = (float*)d_out;
    float* partial = (float*)d_ws;

    const int total = in_sizes[0];                 // 16*3*512*512 = 12582912
    const int nplanes = total / (HH * WW);         // 48

    GaussW gw;
    double g[11], s = 0.0;
    for (int i = 0; i < 11; i++) {
        double d = (double)(i - 5);
        g[i] = exp(-d * d / 4.5);
        s += g[i];
    }
    for (int i = 0; i < 11; i++) gw.w[i] = (float)(g[i] / s);

    dim3 grid(NXT, NYT, nplanes);                  // 16 x 16 x 48 = 12288 blocks
    ssim_tile_kernel<<<grid, NTHREADS, 0, stream>>>(pred, targ, partial, gw);

    const int nblocks = NXT * NYT * nplanes;       // 12288
    const float inv_count = 1.0f / (float)total;
    ssim_finalize_kernel<<<1, 256, 0, stream>>>(partial, nblocks, inv_count, out);
}

// Round 7
// 163.948 us; speedup vs baseline: 1.5614x; 1.1039x over previous
//
#include <hip/hip_runtime.h>
#include <cmath>

#define HH 512
#define WW 512
#define TW 32
#define TH 32          /* output rows per tile */
#define INH 42         /* TH + 10 halo rows */
#define TWP 33         /* padded tile width in pixels: row stride 132 dwords == 4 mod 32 */
#define NTHREADS 256   /* 4 waves; LDS 22.2KB -> 7 blocks/CU = 28 waves/CU static */
#define NXT 16         /* x tiles */
#define NYT 16         /* y tiles */
#define C1F 0.0001f
#define C2F 0.0009f

struct GaussW { float w[11]; };

// R7 = R6 + field-interleaved LDS: hp[row][col][4] = (A,B,EA,EB) per pixel.
// Phase C reads all 4 fields of a pixel in ONE ds_read_b128 (14 instead of
// 56 LDS reads/thread). R6 counters: VALUBusy 63%, FETCH 49MB (cache-fed,
// not memory-bound), occupancy 34% -> LDS-read stream (~224 wave b32/block
// ~= 1300 LDS-pipe cyc) is the biggest non-VALU consumer + issue-slot cost.
// Bank math with +1-pixel row pad (stride 132 dwords == 4 mod 32):
// start bank = (4*row + 4*col) % 32 -> b128 reads AND writes cover all 32
// banks per 8-lane group = optimal 8 cyc/KB, zero conflicts.
// CONFIRMED rule (R1, R5): never pass a min-waves arg to __launch_bounds__
// here - it forces VGPR=40 + scratch spill. LDS alone caps residency.
__global__ __launch_bounds__(NTHREADS) void ssim_tile_kernel(
    const float* __restrict__ pred, const float* __restrict__ targ,
    float* __restrict__ partial, GaussW gw)
{
    __shared__ __align__(16) float hp[INH][TWP][4];
    __shared__ float wred[4];

    const int tid = threadIdx.x;

    // ---- XCD-bijective work remap: lid%8 = hw XCD (round-robin) ----
    const int lid = (blockIdx.z * gridDim.y + blockIdx.y) * gridDim.x + blockIdx.x;
    const int wi  = (lid & 7) * ((NXT * NYT * 48) / 8) + (lid >> 3);
    const int bx  = wi & (NXT - 1);
    const int by  = (wi >> 4) & (NYT - 1);
    const int bz  = wi >> 8;

    const int gx0 = bx * TW;
    const int gy0 = by * TH - 5;
    const size_t plane = (size_t)bz * (size_t)(HH * WW);

    const bool xinterior = (bx > 0) && (bx < NXT - 1);

    // ---- Phase B: horizontal Gaussian on (a,b,a^2,b^2) from global ----
    // 336 tasks: 42 rows x 8 col-groups, each computes 4 output cols.
    if (xinterior) {
        for (int i = tid; i < INH * 8; i += NTHREADS) {
            int r = i >> 3;
            int c0 = (i & 7) << 2;
            int gr = gy0 + r;
            // p[m]/t[m] hold input col c0-6+m, m=0..15 (need m=1..14)
            float p[16], t[16];
            if ((unsigned)gr < (unsigned)HH) {
                const float* prow = pred + plane + (size_t)gr * WW + (gx0 + c0 - 6);
                const float* trow = targ + plane + (size_t)gr * WW + (gx0 + c0 - 6);
                *(float2*)&p[0]  = *(const float2*)(prow);
                *(float4*)&p[2]  = *(const float4*)(prow + 2);
                *(float4*)&p[6]  = *(const float4*)(prow + 6);
                *(float4*)&p[10] = *(const float4*)(prow + 10);
                *(float2*)&p[14] = *(const float2*)(prow + 14);
                *(float2*)&t[0]  = *(const float2*)(trow);
                *(float4*)&t[2]  = *(const float4*)(trow + 2);
                *(float4*)&t[6]  = *(const float4*)(trow + 6);
                *(float4*)&t[10] = *(const float4*)(trow + 10);
                *(float2*)&t[14] = *(const float2*)(trow + 14);
            } else {
                #pragma unroll
                for (int m = 0; m < 16; m++) { p[m] = 0.f; t[m] = 0.f; }
            }

            // in-place butterfly: p[m] <- a = p+t, t[m] <- b = p-t
            #pragma unroll
            for (int m = 1; m < 15; m++) {
                float pv = p[m], tv = t[m];
                p[m] = pv + tv;
                t[m] = pv - tv;
            }

            float sa[4]  = {0,0,0,0}, sb[4]  = {0,0,0,0};
            float saa[4] = {0,0,0,0}, sbb[4] = {0,0,0,0};
            #pragma unroll
            for (int k = 0; k < 11; k++) {
                float wk = gw.w[k];
                #pragma unroll
                for (int o = 0; o < 4; o++) {
                    float av = p[o + k + 1], bv = t[o + k + 1];
                    float wa = wk * av, wb = wk * bv;
                    sa[o]  += wa;
                    sb[o]  += wb;
                    saa[o] += wa * av;
                    sbb[o] += wb * bv;
                }
            }
            #pragma unroll
            for (int o = 0; o < 4; o++)
                *(float4*)&hp[r][c0 + o][0] = make_float4(sa[o], sb[o], saa[o], sbb[o]);
        }
    } else {
        for (int i = tid; i < INH * 8; i += NTHREADS) {
            int r = i >> 3;
            int c0 = (i & 7) << 2;
            int gr = gy0 + r;
            float p[14], t[14];
            if ((unsigned)gr < (unsigned)HH) {
                const size_t rb = plane + (size_t)gr * WW;
                int cbase = gx0 + c0 - 5;
                #pragma unroll
                for (int m = 0; m < 14; m++) {
                    int gc = cbase + m;
                    int cc = min(max(gc, 0), WW - 1);
                    bool in = (unsigned)gc < (unsigned)WW;
                    float pv = pred[rb + cc];
                    float tv = targ[rb + cc];
                    p[m] = in ? pv : 0.f;
                    t[m] = in ? tv : 0.f;
                }
            } else {
                #pragma unroll
                for (int m = 0; m < 14; m++) { p[m] = 0.f; t[m] = 0.f; }
            }

            #pragma unroll
            for (int m = 0; m < 14; m++) {
                float pv = p[m], tv = t[m];
                p[m] = pv + tv;
                t[m] = pv - tv;
            }

            float sa[4]  = {0,0,0,0}, sb[4]  = {0,0,0,0};
            float saa[4] = {0,0,0,0}, sbb[4] = {0,0,0,0};
            #pragma unroll
            for (int k = 0; k < 11; k++) {
                float wk = gw.w[k];
                #pragma unroll
                for (int o = 0; o < 4; o++) {
                    float av = p[o + k], bv = t[o + k];
                    float wa = wk * av, wb = wk * bv;
                    sa[o]  += wa;
                    sb[o]  += wb;
                    saa[o] += wa * av;
                    sbb[o] += wb * bv;
                }
            }
            #pragma unroll
            for (int o = 0; o < 4; o++)
                *(float4*)&hp[r][c0 + o][0] = make_float4(sa[o], sb[o], saa[o], sbb[o]);
        }
    }
    __syncthreads();

    // ---- Phase C: vertical Gaussian, 4 rows x 1 col per thread + SSIM ----
    // 256 threads x 4 outputs = 1024 = 32x32 tile. One b128 read per pixel
    // delivers all 4 fields; 14 reads/thread off one base + imm offsets.
    float local = 0.f;
    {
        const int c0 = tid & 31;            // 0..31
        const int r0 = (tid >> 5) << 2;     // 0..28
        const float* hbase = &hp[r0][c0][0];

        float4 acc[4];
        #pragma unroll
        for (int rr = 0; rr < 4; rr++)
            acc[rr] = make_float4(0.f, 0.f, 0.f, 0.f);

        #pragma unroll
        for (int jj = 0; jj < 14; jj++) {
            float4 v = *(const float4*)(hbase + (size_t)jj * (TWP * 4));
            #pragma unroll
            for (int rr = 0; rr < 4; rr++) {
                int k = jj - rr;
                if (k >= 0 && k < 11) {
                    float wk = gw.w[k];
                    acc[rr].x += wk * v.x;
                    acc[rr].y += wk * v.y;
                    acc[rr].z += wk * v.z;
                    acc[rr].w += wk * v.w;
                }
            }
        }

        #pragma unroll
        for (int rr = 0; rr < 4; rr++) {
            float A  = acc[rr].x, Bv = acc[rr].y;
            float EA = acc[rr].z, EB = acc[rr].w;
            float A2 = A * A, B2 = Bv * Bv;
            float S  = 0.5f  * (A2 + B2);      // mu1^2 + mu2^2
            float P  = 0.25f * (A2 - B2);      // mu1 * mu2
            float Ep = 0.5f  * (EA + EB);      // e11 + e22
            float Ec = 0.25f * (EA - EB);      // e12
            float num = (2.f * P + C1F) * (2.f * (Ec - P) + C2F);
            float den = (S + C1F) * ((Ep - S) + C2F);
            local += num * __builtin_amdgcn_rcpf(den);
        }
    }

    // ---- block reduction (4 waves) ----
    #pragma unroll
    for (int off = 32; off > 0; off >>= 1)
        local += __shfl_down(local, off, 64);
    int lane = tid & 63, wid = tid >> 6;
    if (lane == 0) wred[wid] = local;
    __syncthreads();
    if (tid == 0)
        partial[lid] = wred[0] + wred[1] + wred[2] + wred[3];
}

__global__ __launch_bounds__(256) void ssim_finalize_kernel(
    const float* __restrict__ partial, int n, float inv_count,
    float* __restrict__ out)
{
    __shared__ float sm[4];
    float s = 0.f;
    for (int i = threadIdx.x; i < n; i += 256)
        s += partial[i];
    #pragma unroll
    for (int off = 32; off > 0; off >>= 1)
        s += __shfl_down(s, off, 64);
    int lane = threadIdx.x & 63, wid = threadIdx.x >> 6;
    if (lane == 0) sm[wid] = s;
    __syncthreads();
    if (threadIdx.x == 0)
        out[0] = 1.0f - (sm[0] + sm[1] + sm[2] + sm[3]) * inv_count;
}

extern "C" void kernel_launch(void* const* d_in, const int* in_sizes, int n_in,
                              void* d_out, int out_size, void* d_ws, size_t ws_size,
                              hipStream_t stream)
{
    const float* pred = (const float*)d_in[0];
    const float* targ = (const float*)d_in[1];
    float* out = (float*)d_out;
    float* partial = (float*)d_ws;

    const int total = in_sizes[0];                 // 16*3*512*512 = 12582912
    const int nplanes = total / (HH * WW);         // 48

    GaussW gw;
    double g[11], s = 0.0;
    for (int i = 0; i < 11; i++) {
        double d = (double)(i - 5);
        g[i] = exp(-d * d / 4.5);
        s += g[i];
    }
    for (int i = 0; i < 11; i++) gw.w[i] = (float)(g[i] / s);

    dim3 grid(NXT, NYT, nplanes);                  // 16 x 16 x 48 = 12288 blocks
    ssim_tile_kernel<<<grid, NTHREADS, 0, stream>>>(pred, targ, partial, gw);

    const int nblocks = NXT * NYT * nplanes;       // 12288
    const float inv_count = 1.0f / (float)total;
    ssim_finalize_kernel<<<1, 256, 0, stream>>>(partial, nblocks, inv_count, out);
}

// Round 8
// 154.415 us; speedup vs baseline: 1.6578x; 1.0617x over previous
//
#include <hip/hip_runtime.h>
#include <cmath>

#define HH 512
#define WW 512
#define TW 32
#define TH 32          /* output rows per tile */
#define INH 42         /* TH + 10 halo rows */
#define TWP 33         /* padded tile width in pixels (row base stays 16B-aligned) */
#define NTHREADS 256   /* 4 waves; LDS 22.2KB -> 7 blocks/CU */
#define NXT 16         /* x tiles */
#define NYT 16         /* y tiles */
#define NBLK (NXT * NYT * 48)
#define C1F 0.0001f
#define C2F 0.0009f

struct GaussW { float w[11]; };

// R8 = R7 + bijective pixel-placement swizzle phi(4g+o) = (g^2o) + 8o.
// R7's field-interleave fixed phase-C reads (56 b32 -> 14 b128) but its
// phase-B b128 STORES were 4-way bank-conflicted: store instr o, lanes
// g=0..7 at pixel 4g+o -> quad (16g+4o)%32 = only 2 distinct quads
// (SQ_LDS_BANK_CONFLICT 0 -> 6.19M). phi makes store quad = 4*(g^2o)%32
// (permutation over g: 8 distinct) AND keeps phase-C 8-lane read groups
// on 8 distinct quads (enumerated). o stays the unroll index -> all
// data indexing compile-time (no scratch).
// CONFIRMED rule (R1, R5): never pass a min-waves arg to __launch_bounds__
// here - it forces VGPR=40 + scratch spill. LDS alone caps residency.
__global__ __launch_bounds__(NTHREADS) void ssim_tile_kernel(
    const float* __restrict__ pred, const float* __restrict__ targ,
    float* __restrict__ partial, GaussW gw)
{
    __shared__ __align__(16) float hp[INH][TWP][4];
    __shared__ float wred[4];

    const int tid = threadIdx.x;

    // ---- XCD-bijective work remap: lid%8 = hw XCD (round-robin) ----
    const int lid = (blockIdx.z * gridDim.y + blockIdx.y) * gridDim.x + blockIdx.x;
    const int wi  = (lid & 7) * (NBLK / 8) + (lid >> 3);
    const int bx  = wi & (NXT - 1);
    const int by  = (wi >> 4) & (NYT - 1);
    const int bz  = wi >> 8;

    const int gx0 = bx * TW;
    const int gy0 = by * TH - 5;
    const size_t plane = (size_t)bz * (size_t)(HH * WW);

    const bool xinterior = (bx > 0) && (bx < NXT - 1);

    // ---- Phase B: horizontal Gaussian on (a,b,a^2,b^2) from global ----
    // 336 tasks: 42 rows x 8 col-groups, each computes 4 output cols.
    if (xinterior) {
        for (int i = tid; i < INH * 8; i += NTHREADS) {
            int r = i >> 3;
            int g = i & 7;
            int c0 = g << 2;
            int gr = gy0 + r;
            // p[m]/t[m] hold input col c0-6+m, m=0..15 (need m=1..14)
            float p[16], t[16];
            if ((unsigned)gr < (unsigned)HH) {
                const float* prow = pred + plane + (size_t)gr * WW + (gx0 + c0 - 6);
                const float* trow = targ + plane + (size_t)gr * WW + (gx0 + c0 - 6);
                *(float2*)&p[0]  = *(const float2*)(prow);
                *(float4*)&p[2]  = *(const float4*)(prow + 2);
                *(float4*)&p[6]  = *(const float4*)(prow + 6);
                *(float4*)&p[10] = *(const float4*)(prow + 10);
                *(float2*)&p[14] = *(const float2*)(prow + 14);
                *(float2*)&t[0]  = *(const float2*)(trow);
                *(float4*)&t[2]  = *(const float4*)(trow + 2);
                *(float4*)&t[6]  = *(const float4*)(trow + 6);
                *(float4*)&t[10] = *(const float4*)(trow + 10);
                *(float2*)&t[14] = *(const float2*)(trow + 14);
            } else {
                #pragma unroll
                for (int m = 0; m < 16; m++) { p[m] = 0.f; t[m] = 0.f; }
            }

            // in-place butterfly: p[m] <- a = p+t, t[m] <- b = p-t
            #pragma unroll
            for (int m = 1; m < 15; m++) {
                float pv = p[m], tv = t[m];
                p[m] = pv + tv;
                t[m] = pv - tv;
            }

            float sa[4]  = {0,0,0,0}, sb[4]  = {0,0,0,0};
            float saa[4] = {0,0,0,0}, sbb[4] = {0,0,0,0};
            #pragma unroll
            for (int k = 0; k < 11; k++) {
                float wk = gw.w[k];
                #pragma unroll
                for (int o = 0; o < 4; o++) {
                    float av = p[o + k + 1], bv = t[o + k + 1];
                    float wa = wk * av, wb = wk * bv;
                    sa[o]  += wa;
                    sb[o]  += wb;
                    saa[o] += wa * av;
                    sbb[o] += wb * bv;
                }
            }
            #pragma unroll
            for (int o = 0; o < 4; o++) {
                int phys = (g ^ (o << 1)) + (o << 3);   // phi(c0+o)
                *(float4*)&hp[r][phys][0] = make_float4(sa[o], sb[o], saa[o], sbb[o]);
            }
        }
    } else {
        for (int i = tid; i < INH * 8; i += NTHREADS) {
            int r = i >> 3;
            int g = i & 7;
            int c0 = g << 2;
            int gr = gy0 + r;
            float p[14], t[14];
            if ((unsigned)gr < (unsigned)HH) {
                const size_t rb = plane + (size_t)gr * WW;
                int cbase = gx0 + c0 - 5;
                #pragma unroll
                for (int m = 0; m < 14; m++) {
                    int gc = cbase + m;
                    int cc = min(max(gc, 0), WW - 1);
                    bool in = (unsigned)gc < (unsigned)WW;
                    float pv = pred[rb + cc];
                    float tv = targ[rb + cc];
                    p[m] = in ? pv : 0.f;
                    t[m] = in ? tv : 0.f;
                }
            } else {
                #pragma unroll
                for (int m = 0; m < 14; m++) { p[m] = 0.f; t[m] = 0.f; }
            }

            #pragma unroll
            for (int m = 0; m < 14; m++) {
                float pv = p[m], tv = t[m];
                p[m] = pv + tv;
                t[m] = pv - tv;
            }

            float sa[4]  = {0,0,0,0}, sb[4]  = {0,0,0,0};
            float saa[4] = {0,0,0,0}, sbb[4] = {0,0,0,0};
            #pragma unroll
            for (int k = 0; k < 11; k++) {
                float wk = gw.w[k];
                #pragma unroll
                for (int o = 0; o < 4; o++) {
                    float av = p[o + k], bv = t[o + k];
                    float wa = wk * av, wb = wk * bv;
                    sa[o]  += wa;
                    sb[o]  += wb;
                    saa[o] += wa * av;
                    sbb[o] += wb * bv;
                }
            }
            #pragma unroll
            for (int o = 0; o < 4; o++) {
                int phys = (g ^ (o << 1)) + (o << 3);   // phi(c0+o)
                *(float4*)&hp[r][phys][0] = make_float4(sa[o], sb[o], saa[o], sbb[o]);
            }
        }
    }
    __syncthreads();

    // ---- Phase C: vertical Gaussian, 4 rows x 1 col per thread + SSIM ----
    // 256 threads x 4 outputs = 1024 = 32x32 tile. One b128 read per pixel
    // (all 4 fields); lane c0 reads physical slot phi(c0).
    float local = 0.f;
    {
        const int c0 = tid & 31;            // logical col 0..31
        const int r0 = (tid >> 5) << 2;     // 0..28
        const int pc = ((c0 >> 2) ^ ((c0 & 3) << 1)) + ((c0 & 3) << 3);  // phi(c0)
        const float* hbase = &hp[r0][pc][0];

        float4 acc[4];
        #pragma unroll
        for (int rr = 0; rr < 4; rr++)
            acc[rr] = make_float4(0.f, 0.f, 0.f, 0.f);

        #pragma unroll
        for (int jj = 0; jj < 14; jj++) {
            float4 v = *(const float4*)(hbase + (size_t)jj * (TWP * 4));
            #pragma unroll
            for (int rr = 0; rr < 4; rr++) {
                int k = jj - rr;
                if (k >= 0 && k < 11) {
                    float wk = gw.w[k];
                    acc[rr].x += wk * v.x;
                    acc[rr].y += wk * v.y;
                    acc[rr].z += wk * v.z;
                    acc[rr].w += wk * v.w;
                }
            }
        }

        #pragma unroll
        for (int rr = 0; rr < 4; rr++) {
            float A  = acc[rr].x, Bv = acc[rr].y;
            float EA = acc[rr].z, EB = acc[rr].w;
            float A2 = A * A, B2 = Bv * Bv;
            float S  = 0.5f  * (A2 + B2);      // mu1^2 + mu2^2
            float P  = 0.25f * (A2 - B2);      // mu1 * mu2
            float Ep = 0.5f  * (EA + EB);      // e11 + e22
            float Ec = 0.25f * (EA - EB);      // e12
            float num = (2.f * P + C1F) * (2.f * (Ec - P) + C2F);
            float den = (S + C1F) * ((Ep - S) + C2F);
            local += num * __builtin_amdgcn_rcpf(den);
        }
    }

    // ---- block reduction (4 waves) ----
    #pragma unroll
    for (int off = 32; off > 0; off >>= 1)
        local += __shfl_down(local, off, 64);
    int lane = tid & 63, wid = tid >> 6;
    if (lane == 0) wred[wid] = local;
    __syncthreads();
    if (tid == 0)
        partial[lid] = wred[0] + wred[1] + wred[2] + wred[3];
}

// Compile-time N=12288: 12 independent unrolled float4 loads per thread
// (one memory latency) instead of a 48-iter dependent scalar chain.
__global__ __launch_bounds__(256) void ssim_finalize_kernel(
    const float* __restrict__ partial, float inv_count,
    float* __restrict__ out)
{
    __shared__ float sm[4];
    float s = 0.f;
    #pragma unroll
    for (int i = 0; i < NBLK / 4 / 256; i++) {
        float4 v = *(const float4*)&partial[(threadIdx.x + i * 256) * 4];
        s += (v.x + v.y) + (v.z + v.w);
    }
    #pragma unroll
    for (int off = 32; off > 0; off >>= 1)
        s += __shfl_down(s, off, 64);
    int lane = threadIdx.x & 63, wid = threadIdx.x >> 6;
    if (lane == 0) sm[wid] = s;
    __syncthreads();
    if (threadIdx.x == 0)
        out[0] = 1.0f - (sm[0] + sm[1] + sm[2] + sm[3]) * inv_count;
}

extern "C" void kernel_launch(void* const* d_in, const int* in_sizes, int n_in,
                              void* d_out, int out_size, void* d_ws, size_t ws_size,
                              hipStream_t stream)
{
    const float* pred = (const float*)d_in[0];
    const float* targ = (const float*)d_in[1];
    float* out = (float*)d_out;
    float* partial = (float*)d_ws;

    const int total = in_sizes[0];                 // 16*3*512*512 = 12582912
    const int nplanes = total / (HH * WW);         // 48

    GaussW gw;
    double g[11], s = 0.0;
    for (int i = 0; i < 11; i++) {
        double d = (double)(i - 5);
        g[i] = exp(-d * d / 4.5);
        s += g[i];
    }
    for (int i = 0; i < 11; i++) gw.w[i] = (float)(g[i] / s);

    dim3 grid(NXT, NYT, nplanes);                  // 16 x 16 x 48 = 12288 blocks
    ssim_tile_kernel<<<grid, NTHREADS, 0, stream>>>(pred, targ, partial, gw);

    const float inv_count = 1.0f / (float)total;
    ssim_finalize_kernel<<<1, 256, 0, stream>>>(partial, inv_count, out);
}

// Round 10
// 147.519 us; speedup vs baseline: 1.7352x; 1.0467x over previous
//
#include <hip/hip_runtime.h>
#include <cmath>

#define HH 512
#define WW 512
#define TW 32
#define TH 64          /* output rows per tile: halo redundancy 74/64 = 1.16x (was 1.31x) */
#define INH 74         /* TH + 10 halo rows */
#define TWP 33         /* padded tile width in pixels */
#define NTHREADS 512   /* 8 waves; LDS 39.1KB -> 4 blocks/CU = 32 waves/CU (occupancy cap) */
#define NXT 16         /* x tiles */
#define NYT 8          /* y tiles */
#define NPL 48
#define NBLK (NXT * NYT * NPL)   /* 6144 */
#define C1F 0.0001f
#define C2F 0.0009f

struct GaussW { float w[11]; };

__device__ __forceinline__ void load16a4(const float* __restrict__ p, float v[16]) {
    *(float4*)&v[0]  = *(const float4*)(p);
    *(float4*)&v[4]  = *(const float4*)(p + 4);
    *(float4*)&v[8]  = *(const float4*)(p + 8);
    *(float4*)&v[12] = *(const float4*)(p + 12);
}
__device__ __forceinline__ void load16a2(const float* __restrict__ p, float v[16]) {
    *(float2*)&v[0]  = *(const float2*)(p);
    *(float4*)&v[2]  = *(const float4*)(p + 2);
    *(float4*)&v[6]  = *(const float4*)(p + 6);
    *(float4*)&v[10] = *(const float4*)(p + 10);
    *(float2*)&v[14] = *(const float2*)(p + 14);
}

// R10 = R9 resubmitted verbatim (R9 bench was an infra failure: "container
// failed twice"; kernel re-audited for OOB/alignment/LDS — clean).
// R9 = R8 + (a) TH=64 tile (halo VALU -12%, barriers halved, 4x8=32 waves/CU),
// (b) fully vectorized boundary handling: only g<2 (bx=0) / g>5 (bx=15) touch
// OOB cols; loading a fixed in-bounds 16-float window (col 0 / col 496) makes
// the shift a compile-time constant per g -> zero-mask selects fold away; the
// all-scalar clamp path is deleted.
// R8 lesson: bank conflicts (6.19M->0) were off the critical path; kernel is
// VALU-issue-bound (71% busy). Keep swizzle phi(4g+o)=(g^2o)+8o (free).
// CONFIRMED rule (R1, R5): never pass a min-waves arg to __launch_bounds__ -
// it forces VGPR=40 + scratch spill. LDS alone caps residency.
// VGPR tripwire: must stay <=64 for 8 waves/SIMD (512-reg pool, m69).
__global__ __launch_bounds__(NTHREADS) void ssim_tile_kernel(
    const float* __restrict__ pred, const float* __restrict__ targ,
    float* __restrict__ partial, GaussW gw)
{
    __shared__ __align__(16) float hp[INH][TWP][4];
    __shared__ float wred[8];

    const int tid = threadIdx.x;

    // ---- XCD-bijective work remap: lid%8 = hw XCD (round-robin) ----
    const int lid = (blockIdx.z * gridDim.y + blockIdx.y) * gridDim.x + blockIdx.x;
    const int wi  = (lid & 7) * (NBLK / 8) + (lid >> 3);
    const int bx  = wi & (NXT - 1);
    const int by  = (wi >> 4) & (NYT - 1);
    const int bz  = wi >> 7;

    const int gx0 = bx * TW;
    const int gy0 = by * TH - 5;
    const size_t plane = (size_t)bz * (size_t)(HH * WW);

    const bool lblk = (bx == 0);
    const bool rblk = (bx == NXT - 1);

    // ---- Phase B: horizontal Gaussian on (a,b,a^2,b^2) from global ----
    // 592 tasks: 74 rows x 8 col-groups, each computes 4 output cols.
    // a[j]/b[j] = sum/diff at col gx0+c0-5+j, j=0..13.
    for (int i = tid; i < INH * 8; i += NTHREADS) {
        int r = i >> 3;
        int g = i & 7;
        int c0 = g << 2;
        int gr = gy0 + r;

        if ((unsigned)gr >= (unsigned)HH) {
            float4 z = make_float4(0.f, 0.f, 0.f, 0.f);
            #pragma unroll
            for (int o = 0; o < 4; o++) {
                int phys = (g ^ (o << 1)) + (o << 3);   // phi(c0+o)
                *(float4*)&hp[r][phys][0] = z;
            }
            continue;
        }

        const float* prow = pred + plane + (size_t)gr * WW;
        const float* trow = targ + plane + (size_t)gr * WW;

        float a[14], b[14];
        if (lblk && g < 2) {
            // window = cols 0..15; col(j) = c0-5+j; valid iff col >= 0
            float P[16], T[16];
            load16a4(prow, P);
            load16a4(trow, T);
            if (g == 0) {          // col = j-5, idx = j-5, valid j>=5
                #pragma unroll
                for (int j = 0; j < 14; j++) {
                    float pv = (j >= 5) ? P[j - 5] : 0.f;
                    float tv = (j >= 5) ? T[j - 5] : 0.f;
                    a[j] = pv + tv; b[j] = pv - tv;
                }
            } else {               // g==1: col = j-1, idx = j-1, valid j>=1
                #pragma unroll
                for (int j = 0; j < 14; j++) {
                    float pv = (j >= 1) ? P[j - 1] : 0.f;
                    float tv = (j >= 1) ? T[j - 1] : 0.f;
                    a[j] = pv + tv; b[j] = pv - tv;
                }
            }
        } else if (rblk && g > 5) {
            // window = cols 496..511; col(j) = 480+c0-5+j; valid iff col <= 511
            float P[16], T[16];
            load16a4(prow + (WW - 16), P);
            load16a4(trow + (WW - 16), T);
            if (g == 6) {          // col = 499+j, idx = j+3, valid j<=12
                #pragma unroll
                for (int j = 0; j < 14; j++) {
                    float pv = (j <= 12) ? P[j + 3] : 0.f;
                    float tv = (j <= 12) ? T[j + 3] : 0.f;
                    a[j] = pv + tv; b[j] = pv - tv;
                }
            } else {               // g==7: col = 503+j, idx = j+7, valid j<=8
                #pragma unroll
                for (int j = 0; j < 14; j++) {
                    float pv = (j <= 8) ? P[j + 7] : 0.f;
                    float tv = (j <= 8) ? T[j + 7] : 0.f;
                    a[j] = pv + tv; b[j] = pv - tv;
                }
            }
        } else {
            // interior: window = cols gx0+c0-6 .. +9 (base = 2 mod 4 dwords)
            float P[16], T[16];
            load16a2(prow + gx0 + c0 - 6, P);
            load16a2(trow + gx0 + c0 - 6, T);
            #pragma unroll
            for (int j = 0; j < 14; j++) {
                float pv = P[j + 1], tv = T[j + 1];
                a[j] = pv + tv; b[j] = pv - tv;
            }
        }

        float sa[4]  = {0,0,0,0}, sb[4]  = {0,0,0,0};
        float saa[4] = {0,0,0,0}, sbb[4] = {0,0,0,0};
        #pragma unroll
        for (int k = 0; k < 11; k++) {
            float wk = gw.w[k];
            #pragma unroll
            for (int o = 0; o < 4; o++) {
                float av = a[o + k], bv = b[o + k];
                float wa = wk * av, wb = wk * bv;
                sa[o]  += wa;
                sb[o]  += wb;
                saa[o] += wa * av;
                sbb[o] += wb * bv;
            }
        }
        #pragma unroll
        for (int o = 0; o < 4; o++) {
            int phys = (g ^ (o << 1)) + (o << 3);   // phi(c0+o)
            *(float4*)&hp[r][phys][0] = make_float4(sa[o], sb[o], saa[o], sbb[o]);
        }
    }
    __syncthreads();

    // ---- Phase C: vertical Gaussian, 4 rows x 1 col per thread + SSIM ----
    // 512 threads x 4 outputs = 2048 = 32x64 tile. One b128 read per pixel
    // (all 4 fields); lane c0 reads physical slot phi(c0). Conflict-free
    // (verified R8: 8-lane groups hit 8 distinct bank quads).
    float local = 0.f;
    {
        const int c0 = tid & 31;            // logical col 0..31
        const int r0 = (tid >> 5) << 2;     // 0..60
        const int pc = ((c0 >> 2) ^ ((c0 & 3) << 1)) + ((c0 & 3) << 3);  // phi(c0)
        const float* hbase = &hp[r0][pc][0];

        float4 acc[4];
        #pragma unroll
        for (int rr = 0; rr < 4; rr++)
            acc[rr] = make_float4(0.f, 0.f, 0.f, 0.f);

        #pragma unroll
        for (int jj = 0; jj < 14; jj++) {
            float4 v = *(const float4*)(hbase + (size_t)jj * (TWP * 4));
            #pragma unroll
            for (int rr = 0; rr < 4; rr++) {
                int k = jj - rr;
                if (k >= 0 && k < 11) {
                    float wk = gw.w[k];
                    acc[rr].x += wk * v.x;
                    acc[rr].y += wk * v.y;
                    acc[rr].z += wk * v.z;
                    acc[rr].w += wk * v.w;
                }
            }
        }

        #pragma unroll
        for (int rr = 0; rr < 4; rr++) {
            float A  = acc[rr].x, Bv = acc[rr].y;
            float EA = acc[rr].z, EB = acc[rr].w;
            float A2 = A * A, B2 = Bv * Bv;
            float S  = 0.5f  * (A2 + B2);      // mu1^2 + mu2^2
            float P  = 0.25f * (A2 - B2);      // mu1 * mu2
            float Ep = 0.5f  * (EA + EB);      // e11 + e22
            float Ec = 0.25f * (EA - EB);      // e12
            float num = (2.f * P + C1F) * (2.f * (Ec - P) + C2F);
            float den = (S + C1F) * ((Ep - S) + C2F);
            local += num * __builtin_amdgcn_rcpf(den);
        }
    }

    // ---- block reduction (8 waves) ----
    #pragma unroll
    for (int off = 32; off > 0; off >>= 1)
        local += __shfl_down(local, off, 64);
    int lane = tid & 63, wid = tid >> 6;
    if (lane == 0) wred[wid] = local;
    __syncthreads();
    if (tid == 0) {
        float s = 0.f;
        #pragma unroll
        for (int w2 = 0; w2 < 8; w2++) s += wred[w2];
        partial[lid] = s;
    }
}

// Compile-time N=6144: 6 independent unrolled float4 loads per thread
// (one memory latency) instead of a dependent scalar chain.
__global__ __launch_bounds__(256) void ssim_finalize_kernel(
    const float* __restrict__ partial, float inv_count,
    float* __restrict__ out)
{
    __shared__ float sm[4];
    float s = 0.f;
    #pragma unroll
    for (int i = 0; i < NBLK / 4 / 256; i++) {
        float4 v = *(const float4*)&partial[(threadIdx.x + i * 256) * 4];
        s += (v.x + v.y) + (v.z + v.w);
    }
    #pragma unroll
    for (int off = 32; off > 0; off >>= 1)
        s += __shfl_down(s, off, 64);
    int lane = threadIdx.x & 63, wid = threadIdx.x >> 6;
    if (lane == 0) sm[wid] = s;
    __syncthreads();
    if (threadIdx.x == 0)
        out[0] = 1.0f - (sm[0] + sm[1] + sm[2] + sm[3]) * inv_count;
}

extern "C" void kernel_launch(void* const* d_in, const int* in_sizes, int n_in,
                              void* d_out, int out_size, void* d_ws, size_t ws_size,
                              hipStream_t stream)
{
    const float* pred = (const float*)d_in[0];
    const float* targ = (const float*)d_in[1];
    float* out = (float*)d_out;
    float* partial = (float*)d_ws;

    const int total = in_sizes[0];                 // 16*3*512*512 = 12582912

    GaussW gw;
    double g[11], s = 0.0;
    for (int i = 0; i < 11; i++) {
        double d = (double)(i - 5);
        g[i] = exp(-d * d / 4.5);
        s += g[i];
    }
    for (int i = 0; i < 11; i++) gw.w[i] = (float)(g[i] / s);

    dim3 grid(NXT, NYT, NPL);                      // 16 x 8 x 48 = 6144 blocks
    ssim_tile_kernel<<<grid, NTHREADS, 0, stream>>>(pred, targ, partial, gw);

    const float inv_count = 1.0f / (float)total;
    ssim_finalize_kernel<<<1, 256, 0, stream>>>(partial, inv_count, out);
}

// Round 11
// 143.039 us; speedup vs baseline: 1.7896x; 1.0313x over previous
//
#include <hip/hip_runtime.h>
#include <cmath>

#define HH 512
#define WW 512
#define TW 32
#define TH 64          /* output rows per tile: halo redundancy 74/64 = 1.16x */
#define INH 74         /* TH + 10 halo rows */
#define TWP 33         /* padded tile width in pixels */
#define NTHREADS 512   /* 8 waves; LDS 39.4KB -> 4 blocks/CU = 32 waves/CU cap */
#define NXT 16         /* x tiles */
#define NYT 8          /* y tiles */
#define NPL 48
#define NBLK (NXT * NYT * NPL)   /* 6144 */
#define C1F 0.0001f
#define C2F 0.0009f

typedef float v2f __attribute__((ext_vector_type(2)));

struct GaussW { float w[11]; };

__device__ __forceinline__ void load16a4(const float* __restrict__ p, float v[16]) {
    *(float4*)&v[0]  = *(const float4*)(p);
    *(float4*)&v[4]  = *(const float4*)(p + 4);
    *(float4*)&v[8]  = *(const float4*)(p + 8);
    *(float4*)&v[12] = *(const float4*)(p + 12);
}
__device__ __forceinline__ void load16a2(const float* __restrict__ p, float v[16]) {
    *(float2*)&v[0]  = *(const float2*)(p);
    *(float4*)&v[2]  = *(const float4*)(p + 2);
    *(float4*)&v[6]  = *(const float4*)(p + 6);
    *(float4*)&v[10] = *(const float4*)(p + 10);
    *(float2*)&v[14] = *(const float2*)(p + 14);
}

// R11 = R10 + packed-FP32 math: (a,b) and (A,B)/(EA,EB) pairs expressed as
// ext_vector float2 -> <2 x float> IR -> v_pk_fma_f32/v_pk_mul_f32 (CDNA
// full-rate packed f32). Conv per (k,o): 6 scalar -> 3 packed ops; phase C
// per (jj,rr): 4 -> 2. R10 signature: VALUBusy 66% @ 66.5us, all-scalar
// f32 stream ~580 ops/thread is the dominant issue load.
// Kept from earlier rounds: XCD-bijective remap (FETCH 141->49MB),
// phi(4g+o)=(g^2o)+8o LDS swizzle (conflicts 0), vectorized boundary paths,
// TH=64 tile, unrolled finalize.
// CONFIRMED rule (R1, R5): never pass a min-waves arg to __launch_bounds__ -
// forces VGPR=40 + scratch spill. VGPR tripwire: <=64 for 8 waves/SIMD.
__global__ __launch_bounds__(NTHREADS) void ssim_tile_kernel(
    const float* __restrict__ pred, const float* __restrict__ targ,
    float* __restrict__ partial, GaussW gw)
{
    __shared__ __align__(16) float hp[INH][TWP][4];
    __shared__ float wred[8];

    const int tid = threadIdx.x;

    // ---- XCD-bijective work remap: lid%8 = hw XCD (round-robin) ----
    const int lid = (blockIdx.z * gridDim.y + blockIdx.y) * gridDim.x + blockIdx.x;
    const int wi  = (lid & 7) * (NBLK / 8) + (lid >> 3);
    const int bx  = wi & (NXT - 1);
    const int by  = (wi >> 4) & (NYT - 1);
    const int bz  = wi >> 7;

    const int gx0 = bx * TW;
    const int gy0 = by * TH - 5;
    const size_t plane = (size_t)bz * (size_t)(HH * WW);

    const bool lblk = (bx == 0);
    const bool rblk = (bx == NXT - 1);

    // ---- Phase B: horizontal Gaussian on (a,b,a^2,b^2) from global ----
    // 592 tasks: 74 rows x 8 col-groups, each computes 4 output cols.
    // ab[j] = (p+t, p-t) at col gx0+4g-5+j, j=0..13.
    for (int i = tid; i < INH * 8; i += NTHREADS) {
        int r = i >> 3;
        int g = i & 7;
        int c0 = g << 2;
        int gr = gy0 + r;

        if ((unsigned)gr >= (unsigned)HH) {
            float4 z = make_float4(0.f, 0.f, 0.f, 0.f);
            #pragma unroll
            for (int o = 0; o < 4; o++) {
                int phys = (g ^ (o << 1)) + (o << 3);   // phi(c0+o)
                *(float4*)&hp[r][phys][0] = z;
            }
            continue;
        }

        const float* prow = pred + plane + (size_t)gr * WW;
        const float* trow = targ + plane + (size_t)gr * WW;

        v2f ab[14];
        if (lblk && g < 2) {
            // window = cols 0..15; valid iff col >= 0
            float P[16], T[16];
            load16a4(prow, P);
            load16a4(trow, T);
            if (g == 0) {          // col = j-5, valid j>=5
                #pragma unroll
                for (int j = 0; j < 14; j++) {
                    float pv = (j >= 5) ? P[j - 5] : 0.f;
                    float tv = (j >= 5) ? T[j - 5] : 0.f;
                    ab[j] = (v2f){pv + tv, pv - tv};
                }
            } else {               // g==1: col = j-1, valid j>=1
                #pragma unroll
                for (int j = 0; j < 14; j++) {
                    float pv = (j >= 1) ? P[j - 1] : 0.f;
                    float tv = (j >= 1) ? T[j - 1] : 0.f;
                    ab[j] = (v2f){pv + tv, pv - tv};
                }
            }
        } else if (rblk && g > 5) {
            // window = cols 496..511; valid iff col <= 511
            float P[16], T[16];
            load16a4(prow + (WW - 16), P);
            load16a4(trow + (WW - 16), T);
            if (g == 6) {          // col = 499+j, idx j+3, valid j<=12
                #pragma unroll
                for (int j = 0; j < 14; j++) {
                    float pv = (j <= 12) ? P[j + 3] : 0.f;
                    float tv = (j <= 12) ? T[j + 3] : 0.f;
                    ab[j] = (v2f){pv + tv, pv - tv};
                }
            } else {               // g==7: col = 503+j, idx j+7, valid j<=8
                #pragma unroll
                for (int j = 0; j < 14; j++) {
                    float pv = (j <= 8) ? P[j + 7] : 0.f;
                    float tv = (j <= 8) ? T[j + 7] : 0.f;
                    ab[j] = (v2f){pv + tv, pv - tv};
                }
            }
        } else {
            // interior: window = cols gx0+c0-6 .. +9 (base = 2 mod 4 dwords)
            float P[16], T[16];
            load16a2(prow + gx0 + c0 - 6, P);
            load16a2(trow + gx0 + c0 - 6, T);
            #pragma unroll
            for (int j = 0; j < 14; j++) {
                float pv = P[j + 1], tv = T[j + 1];
                ab[j] = (v2f){pv + tv, pv - tv};
            }
        }

        v2f s1[4], s2[4];
        #pragma unroll
        for (int o = 0; o < 4; o++) { s1[o] = (v2f)(0.f); s2[o] = (v2f)(0.f); }
        #pragma unroll
        for (int k = 0; k < 11; k++) {
            float wk = gw.w[k];
            #pragma unroll
            for (int o = 0; o < 4; o++) {
                v2f v  = ab[o + k];
                v2f wv = wk * v;       // v_pk_mul_f32
                s1[o] += wv;           // v_pk_add_f32
                s2[o] += wv * v;       // v_pk_fma_f32
            }
        }
        #pragma unroll
        for (int o = 0; o < 4; o++) {
            int phys = (g ^ (o << 1)) + (o << 3);   // phi(c0+o)
            *(float4*)&hp[r][phys][0] =
                make_float4(s1[o].x, s1[o].y, s2[o].x, s2[o].y);
        }
    }
    __syncthreads();

    // ---- Phase C: vertical Gaussian, 4 rows x 1 col per thread + SSIM ----
    // 512 threads x 4 outputs = 2048 = 32x64 tile. One b128 read per pixel;
    // packed accumulation: (A,B) and (EA,EB) as v2f.
    float local = 0.f;
    {
        const int c0 = tid & 31;            // logical col 0..31
        const int r0 = (tid >> 5) << 2;     // 0..60
        const int pc = ((c0 >> 2) ^ ((c0 & 3) << 1)) + ((c0 & 3) << 3);  // phi(c0)
        const float* hbase = &hp[r0][pc][0];

        v2f accm[4], acce[4];
        #pragma unroll
        for (int rr = 0; rr < 4; rr++) { accm[rr] = (v2f)(0.f); acce[rr] = (v2f)(0.f); }

        #pragma unroll
        for (int jj = 0; jj < 14; jj++) {
            float4 v = *(const float4*)(hbase + (size_t)jj * (TWP * 4));
            v2f vm = (v2f){v.x, v.y};
            v2f ve = (v2f){v.z, v.w};
            #pragma unroll
            for (int rr = 0; rr < 4; rr++) {
                int k = jj - rr;
                if (k >= 0 && k < 11) {
                    float wk = gw.w[k];
                    accm[rr] += wk * vm;   // v_pk_fma_f32
                    acce[rr] += wk * ve;   // v_pk_fma_f32
                }
            }
        }

        #pragma unroll
        for (int rr = 0; rr < 4; rr++) {
            float A  = accm[rr].x, Bv = accm[rr].y;
            float EA = acce[rr].x, EB = acce[rr].y;
            float A2 = A * A, B2 = Bv * Bv;
            float S  = 0.5f  * (A2 + B2);      // mu1^2 + mu2^2
            float P  = 0.25f * (A2 - B2);      // mu1 * mu2
            float Ep = 0.5f  * (EA + EB);      // e11 + e22
            float Ec = 0.25f * (EA - EB);      // e12
            float num = (2.f * P + C1F) * (2.f * (Ec - P) + C2F);
            float den = (S + C1F) * ((Ep - S) + C2F);
            local += num * __builtin_amdgcn_rcpf(den);
        }
    }

    // ---- block reduction (8 waves) ----
    #pragma unroll
    for (int off = 32; off > 0; off >>= 1)
        local += __shfl_down(local, off, 64);
    int lane = tid & 63, wid = tid >> 6;
    if (lane == 0) wred[wid] = local;
    __syncthreads();
    if (tid == 0) {
        float s = 0.f;
        #pragma unroll
        for (int w2 = 0; w2 < 8; w2++) s += wred[w2];
        partial[lid] = s;
    }
}

// Compile-time N=6144: 6 independent unrolled float4 loads per thread.
__global__ __launch_bounds__(256) void ssim_finalize_kernel(
    const float* __restrict__ partial, float inv_count,
    float* __restrict__ out)
{
    __shared__ float sm[4];
    float s = 0.f;
    #pragma unroll
    for (int i = 0; i < NBLK / 4 / 256; i++) {
        float4 v = *(const float4*)&partial[(threadIdx.x + i * 256) * 4];
        s += (v.x + v.y) + (v.z + v.w);
    }
    #pragma unroll
    for (int off = 32; off > 0; off >>= 1)
        s += __shfl_down(s, off, 64);
    int lane = threadIdx.x & 63, wid = threadIdx.x >> 6;
    if (lane == 0) sm[wid] = s;
    __syncthreads();
    if (threadIdx.x == 0)
        out[0] = 1.0f - (sm[0] + sm[1] + sm[2] + sm[3]) * inv_count;
}

extern "C" void kernel_launch(void* const* d_in, const int* in_sizes, int n_in,
                              void* d_out, int out_size, void* d_ws, size_t ws_size,
                              hipStream_t stream)
{
    const float* pred = (const float*)d_in[0];
    const float* targ = (const float*)d_in[1];
    float* out = (float*)d_out;
    float* partial = (float*)d_ws;

    const int total = in_sizes[0];                 // 16*3*512*512 = 12582912

    GaussW gw;
    double g[11], s = 0.0;
    for (int i = 0; i < 11; i++) {
        double d = (double)(i - 5);
        g[i] = exp(-d * d / 4.5);
        s += g[i];
    }
    for (int i = 0; i < 11; i++) gw.w[i] = (float)(g[i] / s);

    dim3 grid(NXT, NYT, NPL);                      // 16 x 8 x 48 = 6144 blocks
    ssim_tile_kernel<<<grid, NTHREADS, 0, stream>>>(pred, targ, partial, gw);

    const float inv_count = 1.0f / (float)total;
    ssim_finalize_kernel<<<1, 256, 0, stream>>>(partial, inv_count, out);
}